// Round 3
// baseline (537.328 us; speedup 1.0000x reference)
//
#include <hip/hip_runtime.h>

// PWC-Net cost volume, fp32. B=4, C=128, H=256, W=448, 81 shifts.
// out[b, di*9+dj, h, w] = (1/128) * sum_c feat1[b,c,h,w] * feat2[b,c,h+di-4,w+dj-4]
//
// One block per (b,h); 512 threads (8 waves). Lane item it = tid:
// di = it/56, px0 = (it%56)*8 (504 real items). feat2 rows h-4..h+4 staged in
// LDS (1 channel/chunk, double-buffered) via global_load_lds(16B), atoms
// XOR-swizzled p = a ^ ((a>>3)&7) on the GLOBAL source + read offsets
// (LDS dest linear). Pipelined with COUNTED vmcnt + raw s_barrier: stage(t+1)
// loads stay in flight across compute(t); feat1 register-prefetched 1 ch ahead.

#define GLAS(p) ((const __attribute__((address_space(1))) unsigned int*)(p))
#define LDAS(p) ((__attribute__((address_space(3))) unsigned int*)(p))

__global__ __launch_bounds__(512) void cost_volume_kernel(
    const float* __restrict__ feat1,
    const float* __restrict__ feat2,
    const float* __restrict__ zws,
    float* __restrict__ out)
{
    constexpr int C = 128, H = 256, W = 448;
    constexpr int ROWB = 2048;        // 128 16B-atoms per LDS row
    constexpr int BUFB = 9 * ROWB;    // 18432 B per buffer
    constexpr size_t HW = (size_t)H * W;

    __shared__ char f2s[2 * BUFB];    // 36864 B

    const int tid  = threadIdx.x;
    const int wid  = tid >> 6;
    const int lane = tid & 63;

    // XCD-contiguous (b,h) mapping (1024 % 8 == 0 -> bijective)
    const int lin = (blockIdx.x & 7) * ((int)gridDim.x >> 3) + (blockIdx.x >> 3);
    const int b = lin >> 8;
    const int h = lin & 255;

    const int it  = (tid < 504) ? tid : 503;
    const int di  = it / 56;
    const int m   = it - di * 56;
    const int px0 = m << 3;

    // Staging: 18 wave-issues (9 rows x 2 half-rows of 64 atoms).
    // Wave wid takes j = wid, wid+8 (all) and wid+16 (wid<2 only).
    // Lane writes physical atom p = cc*64+lane; logical a = p ^ ((p>>3)&7).
    // Real feat2 atoms: a in [1,112]; halo/pad/out-of-range rows source zws.
    const int lx = lane ^ ((lane >> 3) & 7);
    const int NW = (wid < 2) ? 3 : 2;
    const float* sp[3];
    size_t sstep[3];
    int sdst[3];
#pragma unroll
    for (int k = 0; k < 3; ++k) {
        if (k < NW) {
            const int j    = wid + 8 * k;
            const int r    = j >> 1;
            const int cc   = j & 1;
            const int a    = cc * 64 + lx;
            const int rsrc = h + r - 4;
            const bool ok  = (a >= 1) && (a <= 112) && (rsrc >= 0) && (rsrc < H);
            sp[k]    = ok ? (feat2 + ((size_t)b * C * H + rsrc) * W + (size_t)(a - 1) * 4)
                          : zws;
            sstep[k] = ok ? HW : 0;
            sdst[k]  = r * ROWB + cc * 1024;
        }
    }

    // Window read offsets: atoms a = 2m..2m+3 (cols px0-4 .. px0+11), swizzled.
    int lofs[4];
#pragma unroll
    for (int k = 0; k < 4; ++k) {
        const int a = 2 * m + k;
        lofs[k] = di * ROWB + (a ^ ((a >> 3) & 7)) * 16;
    }

    const float* f1p = feat1 + ((size_t)b * C * H + (size_t)h) * W + px0;

    float acc[9][8];
#pragma unroll
    for (int j = 0; j < 9; ++j)
#pragma unroll
        for (int p = 0; p < 8; ++p) acc[j][p] = 0.0f;

    auto stage = [&](int buf) {
#pragma unroll
        for (int k = 0; k < 3; ++k) {
            if (k < NW) {
                __builtin_amdgcn_global_load_lds(GLAS(sp[k]),
                                                 LDAS(f2s + buf * BUFB + sdst[k]),
                                                 16, 0, 0);
                sp[k] += sstep[k];
            }
        }
    };

    // Prologue: stage(0) + feat1 prefetch for t=0.
    stage(0);
    float4 a0 = *(const float4*)(f1p);
    float4 a1 = *(const float4*)(f1p + 4);
    f1p += HW;

#pragma unroll 1
    for (int t = 0; t < C; ++t) {
        const int buf = t & 1;
        float4 b0, b1;
        if (t + 1 < C) {
            stage(buf ^ 1);                       // NW loads in flight
            b0 = *(const float4*)(f1p);           // +2 loads in flight
            b1 = *(const float4*)(f1p + 4);
            f1p += HW;
            // Wait for stage(t) (and older) only; leave this iter's NW+2 in flight.
            if (wid < 2) asm volatile("s_waitcnt vmcnt(5)" ::: "memory");
            else         asm volatile("s_waitcnt vmcnt(4)" ::: "memory");
        } else {
            asm volatile("s_waitcnt vmcnt(0)" ::: "memory");
        }
        __builtin_amdgcn_s_barrier();             // stage(t) visible to all
        __builtin_amdgcn_sched_barrier(0);        // keep ds_reads below barrier

        const char* lb = f2s + buf * BUFB;
        const float4 w0 = *(const float4*)(lb + lofs[0]);
        const float4 w1 = *(const float4*)(lb + lofs[1]);
        const float4 w2 = *(const float4*)(lb + lofs[2]);
        const float4 w3 = *(const float4*)(lb + lofs[3]);

        const float a[8]  = {a0.x, a0.y, a0.z, a0.w, a1.x, a1.y, a1.z, a1.w};
        const float w[16] = {w0.x, w0.y, w0.z, w0.w, w1.x, w1.y, w1.z, w1.w,
                             w2.x, w2.y, w2.z, w2.w, w3.x, w3.y, w3.z, w3.w};
#pragma unroll
        for (int dj = 0; dj < 9; ++dj)
#pragma unroll
            for (int p = 0; p < 8; ++p)
                acc[dj][p] = fmaf(a[p], w[dj + p], acc[dj][p]);

        __builtin_amdgcn_s_barrier();             // all reads of buf done
        a0 = b0; a1 = b1;
    }

    if (tid < 504) {
        const float s = 1.0f / 128.0f;
        float* ob = out + (((size_t)(b * 81 + di * 9)) * H + h) * W + px0;
#pragma unroll
        for (int dj = 0; dj < 9; ++dj) {
            float4 o0, o1;
            o0.x = acc[dj][0] * s; o0.y = acc[dj][1] * s;
            o0.z = acc[dj][2] * s; o0.w = acc[dj][3] * s;
            o1.x = acc[dj][4] * s; o1.y = acc[dj][5] * s;
            o1.z = acc[dj][6] * s; o1.w = acc[dj][7] * s;
            float* op = ob + (size_t)dj * HW;
            *(float4*)(op)     = o0;
            *(float4*)(op + 4) = o1;
        }
    }
}

extern "C" void kernel_launch(void* const* d_in, const int* in_sizes, int n_in,
                              void* d_out, int out_size, void* d_ws, size_t ws_size,
                              hipStream_t stream) {
    const float* feat1 = (const float*)d_in[0];
    const float* feat2 = (const float*)d_in[1];
    float* out = (float*)d_out;
    // Zero source for halo/pad/out-of-range staging (each lane reads zws[0..16)).
    hipMemsetAsync(d_ws, 0, 256, stream);
    cost_volume_kernel<<<dim3(1024), dim3(512), 0, stream>>>(
        feat1, feat2, (const float*)d_ws, out);
}

// Round 4
// 394.580 us; speedup vs baseline: 1.3618x; 1.3618x over previous
//
#include <hip/hip_runtime.h>

// PWC-Net cost volume, fp32. B=4, C=128, H=256, W=448, 81 shifts.
// out[b, di*9+dj, h, w] = (1/128) * sum_c feat1[b,c,h,w] * feat2[b,c,h+di-4,w+dj-4]
//
// One block per (b,h); 512 threads (8 waves). Lane item it = tid:
// di = it/56, px0 = (it%56)*8 (504 real items). feat2 rows h-4..h+4 staged in
// LDS (1 channel/chunk, double-buffered) via global_load_lds(16B), atoms
// XOR-swizzled p = a ^ ((a>>3)&7) on the GLOBAL source + read offsets.
//
// Schedule (drain-old-only): per iteration
//   s_waitcnt vmcnt(0)   <- drains stage(t)+feat1(t), issued ONE ITERATION AGO
//   s_barrier            <- single barrier/iter: publishes stage(t), and proves
//                           all waves finished reading buf^1 (compute(t-1))
//   issue stage(t+1) + feat1(t+1)   <- stays in flight across compute(t)
//   compute(t)
// so no just-issued load is ever drained (the R1/R2 stall).

#define GLAS(p) ((const __attribute__((address_space(1))) unsigned int*)(p))
#define LDAS(p) ((__attribute__((address_space(3))) unsigned int*)(p))

__global__ __launch_bounds__(512, 4) void cost_volume_kernel(
    const float* __restrict__ feat1,
    const float* __restrict__ feat2,
    const float* __restrict__ zws,
    float* __restrict__ out)
{
    constexpr int C = 128, H = 256, W = 448;
    constexpr int ROWB = 2048;        // 128 16B-atoms per LDS row
    constexpr int BUFB = 9 * ROWB;    // 18432 B per buffer
    constexpr size_t HW = (size_t)H * W;

    __shared__ char f2s[2 * BUFB];    // 36864 B

    const int tid  = threadIdx.x;
    const int wid  = tid >> 6;
    const int lane = tid & 63;

    // XCD-contiguous (b,h) mapping (1024 % 8 == 0 -> bijective)
    const int lin = (blockIdx.x & 7) * ((int)gridDim.x >> 3) + (blockIdx.x >> 3);
    const int b = lin >> 8;
    const int h = lin & 255;

    const int it  = (tid < 504) ? tid : 503;
    const int di  = it / 56;
    const int m   = it - di * 56;
    const int px0 = m << 3;

    // Staging: 18 wave-issues (9 rows x 2 half-rows of 64 atoms).
    // Wave wid takes j = wid, wid+8 (all) and wid+16 (wid<2 only).
    // Lane writes physical atom p = cc*64+lane; logical a = p ^ ((p>>3)&7).
    // Real feat2 atoms: a in [1,112]; halo/pad/out-of-range rows source zws.
    const int lx = lane ^ ((lane >> 3) & 7);
    const int NW = (wid < 2) ? 3 : 2;
    const float* sp[3];
    size_t sstep[3];
    int sdst[3];
#pragma unroll
    for (int k = 0; k < 3; ++k) {
        if (k < NW) {
            const int j    = wid + 8 * k;
            const int r    = j >> 1;
            const int cc   = j & 1;
            const int a    = cc * 64 + lx;
            const int rsrc = h + r - 4;
            const bool ok  = (a >= 1) && (a <= 112) && (rsrc >= 0) && (rsrc < H);
            sp[k]    = ok ? (feat2 + ((size_t)b * C * H + rsrc) * W + (size_t)(a - 1) * 4)
                          : zws;
            sstep[k] = ok ? HW : 0;
            sdst[k]  = r * ROWB + cc * 1024;
        }
    }

    // Window read offsets: atoms a = 2m..2m+3 (cols px0-4 .. px0+11), swizzled.
    int lofs[4];
#pragma unroll
    for (int k = 0; k < 4; ++k) {
        const int a = 2 * m + k;
        lofs[k] = di * ROWB + (a ^ ((a >> 3) & 7)) * 16;
    }

    const float* f1p = feat1 + ((size_t)b * C * H + (size_t)h) * W + px0;

    float acc[9][8];
#pragma unroll
    for (int j = 0; j < 9; ++j)
#pragma unroll
        for (int p = 0; p < 8; ++p) acc[j][p] = 0.0f;

    auto stage = [&](int buf) {
#pragma unroll
        for (int k = 0; k < 3; ++k) {
            if (k < NW) {
                __builtin_amdgcn_global_load_lds(GLAS(sp[k]),
                                                 LDAS(f2s + buf * BUFB + sdst[k]),
                                                 16, 0, 0);
                sp[k] += sstep[k];
            }
        }
    };

    // Prologue: stage(0) + feat1(0) prefetch (this pair is the only exposed drain).
    stage(0);
    float4 a0 = *(const float4*)(f1p);
    float4 a1 = *(const float4*)(f1p + 4);
    f1p += HW;

    for (int t = 0; t < C; ++t) {
        const int buf = t & 1;

        // Drain loads issued one iteration ago, then the single barrier.
        asm volatile("s_waitcnt vmcnt(0)" ::: "memory");
        __builtin_amdgcn_s_barrier();
        __builtin_amdgcn_sched_barrier(0);

        float4 b0, b1;
        if (t + 1 < C) {
            stage(buf ^ 1);                 // in flight across compute(t)
            b0 = *(const float4*)(f1p);
            b1 = *(const float4*)(f1p + 4);
            f1p += HW;
        }

        const char* lb = f2s + buf * BUFB;
        const float4 w0 = *(const float4*)(lb + lofs[0]);
        const float4 w1 = *(const float4*)(lb + lofs[1]);
        const float4 w2 = *(const float4*)(lb + lofs[2]);
        const float4 w3 = *(const float4*)(lb + lofs[3]);

        const float a[8]  = {a0.x, a0.y, a0.z, a0.w, a1.x, a1.y, a1.z, a1.w};
        const float w[16] = {w0.x, w0.y, w0.z, w0.w, w1.x, w1.y, w1.z, w1.w,
                             w2.x, w2.y, w2.z, w2.w, w3.x, w3.y, w3.z, w3.w};
#pragma unroll
        for (int dj = 0; dj < 9; ++dj)
#pragma unroll
            for (int p = 0; p < 8; ++p)
                acc[dj][p] = fmaf(a[p], w[dj + p], acc[dj][p]);

        if (t + 1 < C) { a0 = b0; a1 = b1; }
    }

    if (tid < 504) {
        const float s = 1.0f / 128.0f;
        float* ob = out + (((size_t)(b * 81 + di * 9)) * H + h) * W + px0;
#pragma unroll
        for (int dj = 0; dj < 9; ++dj) {
            float4 o0, o1;
            o0.x = acc[dj][0] * s; o0.y = acc[dj][1] * s;
            o0.z = acc[dj][2] * s; o0.w = acc[dj][3] * s;
            o1.x = acc[dj][4] * s; o1.y = acc[dj][5] * s;
            o1.z = acc[dj][6] * s; o1.w = acc[dj][7] * s;
            float* op = ob + (size_t)dj * HW;
            *(float4*)(op)     = o0;
            *(float4*)(op + 4) = o1;
        }
    }
}

extern "C" void kernel_launch(void* const* d_in, const int* in_sizes, int n_in,
                              void* d_out, int out_size, void* d_ws, size_t ws_size,
                              hipStream_t stream) {
    const float* feat1 = (const float*)d_in[0];
    const float* feat2 = (const float*)d_in[1];
    float* out = (float*)d_out;
    // Zero source for halo/pad/out-of-range staging (each lane reads zws[0..16)).
    hipMemsetAsync(d_ws, 0, 256, stream);
    cost_volume_kernel<<<dim3(1024), dim3(512), 0, stream>>>(
        feat1, feat2, (const float*)d_ws, out);
}